// Round 1
// baseline (314.970 us; speedup 1.0000x reference)
//
#include <hip/hip_runtime.h>
#include <hip/hip_bf16.h>

#define N_NODES 100000
#define DN      256
#define DE      128
#define DOUT    256
#define M1      32768
#define BSZ     8192
#define E1      327680
#define E2      81920
#define DIN     640
#define DAGG    384

#define CDIV(a,b) (((a)+(b)-1)/(b))

// ---- bookkeeping kernels -------------------------------------------------

__global__ __launch_bounds__(256) void mark_kernel(const int* __restrict__ self2,
                                                   int* __restrict__ mark) {
  int i = blockIdx.x * 256 + threadIdx.x;
  if (i < BSZ) mark[self2[i]] = 1;
}

__global__ __launch_bounds__(256) void compact_kernel(const int* __restrict__ mark,
                                                      const int* __restrict__ self1,
                                                      int* __restrict__ remap,
                                                      int* __restrict__ needed,
                                                      int* __restrict__ selfrow1,
                                                      int* __restrict__ nn) {
  int m = blockIdx.x * 256 + threadIdx.x;
  if (m >= M1) return;
  if (mark[m]) {
    int p = atomicAdd(nn, 1);
    remap[m] = p;
    needed[p] = m;
    selfrow1[p] = self1[m];
  } else {
    remap[m] = -1;
  }
}

__global__ __launch_bounds__(256) void count_kernel(const int* __restrict__ seg,
                                                    const int* __restrict__ mark,
                                                    int* __restrict__ cnt, int nE) {
  int e = blockIdx.x * 256 + threadIdx.x;
  if (e >= nE) return;
  int s = seg[e];
  if (!mark || mark[s]) atomicAdd(&cnt[s], 1);
}

// single-block exclusive scan of n ints (n must be divisible by 1024)
__global__ __launch_bounds__(1024) void scan_excl_kernel(const int* __restrict__ cnt,
                                                         int* __restrict__ off,
                                                         int* __restrict__ cur, int n) {
  int t = threadIdx.x;
  int per = n >> 10;
  int base = t * per;
  int s = 0;
  for (int j = 0; j < per; ++j) s += cnt[base + j];
  int lane = t & 63, wid = t >> 6;
  int v = s;
  for (int d = 1; d < 64; d <<= 1) {
    int u = __shfl_up(v, d);
    if (lane >= d) v += u;
  }
  __shared__ int wsum[16];
  if (lane == 63) wsum[wid] = v;
  __syncthreads();
  if (t == 0) {
    int run = 0;
    for (int wi = 0; wi < 16; ++wi) { int x = wsum[wi]; wsum[wi] = run; run += x; }
    off[n] = run;
  }
  __syncthreads();
  int excl = wsum[wid] + (v - s);
  int run = excl;
  for (int j = 0; j < per; ++j) {
    off[base + j] = run;
    cur[base + j] = run;
    run += cnt[base + j];
  }
}

__global__ __launch_bounds__(256) void scatter_kernel(const int* __restrict__ seg,
                                                      const int* __restrict__ mark,
                                                      int* __restrict__ cur,
                                                      int* __restrict__ order, int nE) {
  int e = blockIdx.x * 256 + threadIdx.x;
  if (e >= nE) return;
  int s = seg[e];
  if (!mark || mark[s]) {
    int p = atomicAdd(&cur[s], 1);
    order[p] = e;
  }
}

__global__ __launch_bounds__(256) void selfrow2_kernel(const int* __restrict__ self2,
                                                       const int* __restrict__ remap,
                                                       int* __restrict__ selfrow2) {
  int i = blockIdx.x * 256 + threadIdx.x;
  if (i < BSZ) selfrow2[i] = remap[self2[i]];
}

// ---- aggregation: one block (384 thr) per output segment -----------------
// agg row layout: [0..255] = sum of gathered node feats, [256..383] = sum of edge feats

__global__ __launch_bounds__(384) void agg_kernel(const int* __restrict__ needed,
                                                  const int* __restrict__ nn_dev,
                                                  const int* __restrict__ off,
                                                  const int* __restrict__ order,
                                                  const int* __restrict__ from_idx,
                                                  const float* __restrict__ nf,
                                                  const float* __restrict__ ef,
                                                  float* __restrict__ aggout) {
  int r = blockIdx.x;
  if (nn_dev && r >= *nn_dev) return;
  int seg = needed ? needed[r] : r;
  int t = threadIdx.x;
  int e0 = off[seg], e1 = off[seg + 1];
  float acc = 0.f;
  if (t < 256) {
    for (int j = e0; j < e1; ++j) {
      int fi = from_idx[order[j]];
      acc += nf[(size_t)fi * 256 + t];
    }
  } else {
    int te = t - 256;
    for (int j = e0; j < e1; ++j) {
      int e = order[j];
      acc += ef[(size_t)e * 128 + te];
    }
  }
  aggout[(size_t)r * DAGG + t] = acc;
}

// ---- fused gather+concat GEMM: out[r,:] = relu([tab[rowidx[r]] | agg[r]] @ W^T) ----
// tab rows: 256 f32; agg rows: 384 f32; W: [256][640] row-major. Tile 64x64, BK=16.

__global__ __launch_bounds__(256) void gemm_cat_kernel(const float* __restrict__ tab,
                                                       const int* __restrict__ rowidx,
                                                       const float* __restrict__ agg,
                                                       const float* __restrict__ W,
                                                       float* __restrict__ out,
                                                       const int* __restrict__ nn_dev,
                                                       int nrows_c) {
  int nrows = nn_dev ? *nn_dev : nrows_c;
  int row0 = blockIdx.x * 64;
  if (row0 >= nrows) return;
  int col0 = blockIdx.y * 64;

  __shared__ float As[16][68];
  __shared__ float Bs[16][68];

  int t = threadIdx.x;
  int tx = t & 15, ty = t >> 4;

  float c[4][4] = {{0.f}};

  // A-load: thread t loads one float4: local row ar = t>>2, k-group akg = (t&3)*4
  int ar = t >> 2, akg = (t & 3) * 4;
  int grow = row0 + ar;
  bool avalid = grow < nrows;
  int ridx = avalid ? rowidx[grow] : 0;
  const float* tabrow = tab + (size_t)ridx * 256;
  const float* aggrow = agg + (size_t)grow * DAGG;
  // B-load: col bn_ = t>>2, k-group bkg = (t&3)*4
  int bn_ = t >> 2, bkg = (t & 3) * 4;
  const float* wrow = W + (size_t)(col0 + bn_) * DIN;

  for (int k0 = 0; k0 < DIN; k0 += 16) {
    float4 av = make_float4(0.f, 0.f, 0.f, 0.f);
    if (avalid) {
      int k = k0 + akg;
      const float* src = (k < 256) ? (tabrow + k) : (aggrow + (k - 256));
      av = *reinterpret_cast<const float4*>(src);
    }
    float4 bv = *reinterpret_cast<const float4*>(wrow + k0 + bkg);

    As[akg + 0][ar] = av.x; As[akg + 1][ar] = av.y;
    As[akg + 2][ar] = av.z; As[akg + 3][ar] = av.w;
    Bs[bkg + 0][bn_] = bv.x; Bs[bkg + 1][bn_] = bv.y;
    Bs[bkg + 2][bn_] = bv.z; Bs[bkg + 3][bn_] = bv.w;
    __syncthreads();

#pragma unroll
    for (int kk = 0; kk < 16; ++kk) {
      float a[4], b[4];
#pragma unroll
      for (int i = 0; i < 4; ++i) a[i] = As[kk][ty * 4 + i];
#pragma unroll
      for (int j = 0; j < 4; ++j) b[j] = Bs[kk][tx * 4 + j];
#pragma unroll
      for (int i = 0; i < 4; ++i)
#pragma unroll
        for (int j = 0; j < 4; ++j) c[i][j] += a[i] * b[j];
    }
    __syncthreads();
  }

#pragma unroll
  for (int i = 0; i < 4; ++i) {
    int r = row0 + ty * 4 + i;
    if (r < nrows) {
      float4 v;
      v.x = fmaxf(c[i][0], 0.f);
      v.y = fmaxf(c[i][1], 0.f);
      v.z = fmaxf(c[i][2], 0.f);
      v.w = fmaxf(c[i][3], 0.f);
      *reinterpret_cast<float4*>(out + (size_t)r * DOUT + col0 + tx * 4) = v;
    }
  }
}

// ---- launcher ------------------------------------------------------------

extern "C" void kernel_launch(void* const* d_in, const int* in_sizes, int n_in,
                              void* d_out, int out_size, void* d_ws, size_t ws_size,
                              hipStream_t stream) {
  const float* nf   = (const float*)d_in[0];
  const float* ef1  = (const float*)d_in[1];
  const float* ef2  = (const float*)d_in[2];
  const float* W1   = (const float*)d_in[3];
  const float* W2   = (const float*)d_in[4];
  const int* from1  = (const int*)d_in[5];
  const int* seg1   = (const int*)d_in[6];
  const int* self1  = (const int*)d_in[7];
  const int* from2  = (const int*)d_in[8];
  const int* seg2   = (const int*)d_in[9];
  const int* self2  = (const int*)d_in[10];
  float* out = (float*)d_out;

  char* w = (char*)d_ws;
  size_t o = 0;
  auto take = [&](size_t nb) -> char* {
    char* p = w + o;
    o += (nb + 255) & ~(size_t)255;
    return p;
  };
  // zero-region (one memset): cnt1, cnt2, mark, nn — all multiples of 256B
  int* cnt1 = (int*)take((size_t)M1 * 4);
  int* cnt2 = (int*)take((size_t)BSZ * 4);
  int* mark = (int*)take((size_t)M1 * 4);
  int* nn   = (int*)take(256);
  size_t zero_bytes = o;
  int* off1     = (int*)take((size_t)(M1 + 1) * 4);
  int* cur1     = (int*)take((size_t)M1 * 4);
  int* order1   = (int*)take((size_t)E1 * 4);
  int* remap    = (int*)take((size_t)M1 * 4);
  int* needed   = (int*)take((size_t)8192 * 4);
  int* selfrow1 = (int*)take((size_t)8192 * 4);
  int* selfrow2 = (int*)take((size_t)8192 * 4);
  int* off2     = (int*)take((size_t)(BSZ + 1) * 4);
  int* cur2     = (int*)take((size_t)BSZ * 4);
  int* order2   = (int*)take((size_t)E2 * 4);
  float* agg1c  = (float*)take((size_t)8192 * DAGG * 4);
  float* h1c    = (float*)take((size_t)8192 * DOUT * 4);
  float* agg2   = (float*)take((size_t)8192 * DAGG * 4);

  hipMemsetAsync(d_ws, 0, zero_bytes, stream);

  mark_kernel<<<CDIV(BSZ, 256), 256, 0, stream>>>(self2, mark);
  compact_kernel<<<CDIV(M1, 256), 256, 0, stream>>>(mark, self1, remap, needed, selfrow1, nn);
  count_kernel<<<CDIV(E1, 256), 256, 0, stream>>>(seg1, mark, cnt1, E1);
  scan_excl_kernel<<<1, 1024, 0, stream>>>(cnt1, off1, cur1, M1);
  scatter_kernel<<<CDIV(E1, 256), 256, 0, stream>>>(seg1, mark, cur1, order1, E1);
  agg_kernel<<<8192, 384, 0, stream>>>(needed, nn, off1, order1, from1, nf, ef1, agg1c);

  selfrow2_kernel<<<CDIV(BSZ, 256), 256, 0, stream>>>(self2, remap, selfrow2);
  count_kernel<<<CDIV(E2, 256), 256, 0, stream>>>(seg2, nullptr, cnt2, E2);
  scan_excl_kernel<<<1, 1024, 0, stream>>>(cnt2, off2, cur2, BSZ);
  scatter_kernel<<<CDIV(E2, 256), 256, 0, stream>>>(seg2, nullptr, cur2, order2, E2);
  agg_kernel<<<8192, 384, 0, stream>>>(nullptr, nullptr, off2, order2, from2, nf, ef2, agg2);

  gemm_cat_kernel<<<dim3(128, 4), 256, 0, stream>>>(nf, selfrow1, agg1c, W1, h1c, nn, 0);
  gemm_cat_kernel<<<dim3(128, 4), 256, 0, stream>>>(h1c, selfrow2, agg2, W2, out, nullptr, BSZ);
}

// Round 2
// 238.093 us; speedup vs baseline: 1.3229x; 1.3229x over previous
//
#include <hip/hip_runtime.h>
#include <hip/hip_bf16.h>

#define N_NODES 100000
#define DN      256
#define DE      128
#define DOUT    256
#define M1      32768
#define BSZ     8192
#define E1      327680
#define E2      81920
#define DIN     640
#define DAGG    384

#define CDIV(a,b) (((a)+(b)-1)/(b))

typedef __attribute__((ext_vector_type(8))) short bf16x8;
typedef __attribute__((ext_vector_type(4))) float f32x4;

__device__ __forceinline__ unsigned short f32_bf16(float f) {
  unsigned u = __float_as_uint(f);
  unsigned r = (u + 0x7FFF + ((u >> 16) & 1)) >> 16;
  return (unsigned short)r;
}

// ---- bookkeeping kernels -------------------------------------------------

__global__ __launch_bounds__(256) void mark_kernel(const int* __restrict__ self2,
                                                   int* __restrict__ mark) {
  int i = blockIdx.x * 256 + threadIdx.x;
  if (i < BSZ) mark[self2[i]] = 1;
}

__global__ __launch_bounds__(256) void compact_kernel(const int* __restrict__ mark,
                                                      const int* __restrict__ self1,
                                                      int* __restrict__ remap,
                                                      int* __restrict__ needed,
                                                      int* __restrict__ selfrow1,
                                                      int* __restrict__ nn) {
  int m = blockIdx.x * 256 + threadIdx.x;
  if (m >= M1) return;
  if (mark[m]) {
    int p = atomicAdd(nn, 1);
    remap[m] = p;
    needed[p] = m;
    selfrow1[p] = self1[m];
  } else {
    remap[m] = -1;
  }
}

__global__ __launch_bounds__(256) void count_both_kernel(const int* __restrict__ seg1,
                                                         const int* __restrict__ mark,
                                                         int* __restrict__ cnt1,
                                                         const int* __restrict__ seg2,
                                                         int* __restrict__ cnt2) {
  int e = blockIdx.x * 256 + threadIdx.x;
  if (e < E1) {
    int s = seg1[e];
    if (mark[s]) atomicAdd(&cnt1[s], 1);
  } else if (e < E1 + E2) {
    int s = seg2[e - E1];
    atomicAdd(&cnt2[s], 1);
  }
}

// block 0: scan cnt1 (n=M1), block 1: scan cnt2 (n=BSZ). n divisible by 1024.
__global__ __launch_bounds__(1024) void scan_both_kernel(const int* __restrict__ cnt1,
                                                         int* __restrict__ off1,
                                                         int* __restrict__ cur1,
                                                         const int* __restrict__ cnt2,
                                                         int* __restrict__ off2,
                                                         int* __restrict__ cur2) {
  const int* cnt; int* off; int* cur; int n;
  if (blockIdx.x == 0) { cnt = cnt1; off = off1; cur = cur1; n = M1; }
  else                 { cnt = cnt2; off = off2; cur = cur2; n = BSZ; }
  int t = threadIdx.x;
  int per = n >> 10;
  int base = t * per;
  int s = 0;
  for (int j = 0; j < per; ++j) s += cnt[base + j];
  int lane = t & 63, wid = t >> 6;
  int v = s;
  for (int d = 1; d < 64; d <<= 1) {
    int u = __shfl_up(v, d);
    if (lane >= d) v += u;
  }
  __shared__ int wsum[16];
  if (lane == 63) wsum[wid] = v;
  __syncthreads();
  if (t == 0) {
    int run = 0;
    for (int wi = 0; wi < 16; ++wi) { int x = wsum[wi]; wsum[wi] = run; run += x; }
    off[n] = run;
  }
  __syncthreads();
  int excl = wsum[wid] + (v - s);
  int run = excl;
  for (int j = 0; j < per; ++j) {
    off[base + j] = run;
    cur[base + j] = run;
    run += cnt[base + j];
  }
}

__global__ __launch_bounds__(256) void scatter_both_kernel(const int* __restrict__ seg1,
                                                           const int* __restrict__ mark,
                                                           int* __restrict__ cur1,
                                                           int* __restrict__ order1,
                                                           const int* __restrict__ seg2,
                                                           int* __restrict__ cur2,
                                                           int* __restrict__ order2) {
  int e = blockIdx.x * 256 + threadIdx.x;
  if (e < E1) {
    int s = seg1[e];
    if (mark[s]) {
      int p = atomicAdd(&cur1[s], 1);
      order1[p] = e;
    }
  } else if (e < E1 + E2) {
    int e2 = e - E1;
    int s = seg2[e2];
    int p = atomicAdd(&cur2[s], 1);
    order2[p] = e2;
  }
}

// ---- aggregation: one block (384 thr) per output segment, both layers ----
// agg row layout (bf16): [0..255] sum of gathered node feats, [256..383] sum of edge feats

__global__ __launch_bounds__(384) void agg_both_kernel(const int* __restrict__ needed,
                                                       const int* __restrict__ nn_dev,
                                                       const int* __restrict__ off1,
                                                       const int* __restrict__ order1,
                                                       const int* __restrict__ from1,
                                                       const float* __restrict__ ef1,
                                                       unsigned short* __restrict__ agg1,
                                                       const int* __restrict__ off2,
                                                       const int* __restrict__ order2,
                                                       const int* __restrict__ from2,
                                                       const float* __restrict__ ef2,
                                                       unsigned short* __restrict__ agg2,
                                                       const float* __restrict__ nf) {
  int b = blockIdx.x;
  const int* off; const int* order; const int* from_idx; const float* ef;
  unsigned short* aggout; int r, seg;
  if (b < 8192) {
    if (b >= *nn_dev) return;
    r = b; seg = needed[b];
    off = off1; order = order1; from_idx = from1; ef = ef1; aggout = agg1;
  } else {
    r = b - 8192; seg = r;
    off = off2; order = order2; from_idx = from2; ef = ef2; aggout = agg2;
  }
  int t = threadIdx.x;
  int e0 = off[seg], e1 = off[seg + 1];
  float acc = 0.f;
  if (t < 256) {
    for (int j = e0; j < e1; ++j) {
      int fi = from_idx[order[j]];
      acc += nf[(size_t)fi * 256 + t];
    }
  } else {
    int te = t - 256;
    for (int j = e0; j < e1; ++j) {
      int e = order[j];
      acc += ef[(size_t)e * 128 + te];
    }
  }
  aggout[(size_t)r * DAGG + t] = f32_bf16(acc);
}

// ---- W f32 -> bf16 conversion (both weight matrices, flat) ---------------

#define WELEMS (DOUT * DIN)

__global__ __launch_bounds__(256) void convw_kernel(const float* __restrict__ W1,
                                                    const float* __restrict__ W2,
                                                    unsigned short* __restrict__ Wb1,
                                                    unsigned short* __restrict__ Wb2) {
  int i = (blockIdx.x * 256 + threadIdx.x) * 4;
  const float* s; unsigned short* d; int o;
  if (i < WELEMS) { s = W1; d = Wb1; o = i; }
  else if (i < 2 * WELEMS) { s = W2; d = Wb2; o = i - WELEMS; }
  else return;
  f32x4 v = *reinterpret_cast<const f32x4*>(s + o);
  d[o + 0] = f32_bf16(v[0]);
  d[o + 1] = f32_bf16(v[1]);
  d[o + 2] = f32_bf16(v[2]);
  d[o + 3] = f32_bf16(v[3]);
}

// ---- MFMA GEMM: out[r,:] = relu([tabrow(r) | agg[r]] @ W^T) --------------
// MODE 0 (layer1): table = nf (f32), row = i1[r];        out = bf16 h1
// MODE 1 (layer2): table = h1 (bf16), row = i2[i1[r]];   out = f32 final
// Tile: BM=128, BN=64, BK=32; 4 waves in 2x2; per wave 4x2 frags of 16x16.

template<int MODE>
__global__ __launch_bounds__(256) void gemm_mfma_kernel(const float* __restrict__ tabf,
                                                        const unsigned short* __restrict__ tabb,
                                                        const int* __restrict__ i1,
                                                        const int* __restrict__ i2,
                                                        const unsigned short* __restrict__ agg,
                                                        const unsigned short* __restrict__ Wb,
                                                        float* __restrict__ outf,
                                                        unsigned short* __restrict__ outb,
                                                        const int* __restrict__ nn_dev,
                                                        int nrows_c) {
  const int nrows = nn_dev ? *nn_dev : nrows_c;
  const int row0 = blockIdx.x * 128;
  if (row0 >= nrows) return;
  const int col0 = blockIdx.y * 64;

  __shared__ unsigned short As[128][40];  // 80B row stride: 16B-aligned, low conflict
  __shared__ unsigned short Bs[64][40];

  const int t = threadIdx.x;
  const int lane = t & 63, wid = t >> 6;
  const int wm = wid >> 1, wn = wid & 1;

  // staging geometry: thread t stages A rows (t>>2) and (t>>2)+64, k-oct (t&3)*8
  const int arow = t >> 2;
  const int akg = (t & 3) * 8;
  const int grow0 = row0 + arow;
  const int grow1 = row0 + arow + 64;
  int ga0 = -1, ga1 = -1;
  if (grow0 < nrows) { int x = i1[grow0]; ga0 = (MODE == 1) ? i2[x] : x; }
  if (grow1 < nrows) { int x = i1[grow1]; ga1 = (MODE == 1) ? i2[x] : x; }

  const int bn_ = t >> 2;  // B stage: col (t>>2), same k-oct
  const unsigned short* wrow = Wb + (size_t)(col0 + bn_) * DIN;

  f32x4 acc[4][2];
#pragma unroll
  for (int m = 0; m < 4; ++m)
#pragma unroll
    for (int n = 0; n < 2; ++n) acc[m][n] = (f32x4)0.f;

  auto loadA = [&](int ga, int grow, int k) -> bf16x8 {
    bf16x8 v = (bf16x8)(short)0;
    if (ga < 0) return v;
    if (k < 256) {
      if (MODE == 0) {
        const float* s = tabf + (size_t)ga * 256 + k;
        f32x4 x0 = *reinterpret_cast<const f32x4*>(s);
        f32x4 x1 = *reinterpret_cast<const f32x4*>(s + 4);
#pragma unroll
        for (int j = 0; j < 4; ++j) {
          v[j] = (short)f32_bf16(x0[j]);
          v[4 + j] = (short)f32_bf16(x1[j]);
        }
      } else {
        v = *reinterpret_cast<const bf16x8*>(tabb + (size_t)ga * 256 + k);
      }
    } else {
      v = *reinterpret_cast<const bf16x8*>(agg + (size_t)grow * DAGG + (k - 256));
    }
    return v;
  };

  for (int k0 = 0; k0 < DIN; k0 += 32) {
    *reinterpret_cast<bf16x8*>(&As[arow][akg]) = loadA(ga0, grow0, k0 + akg);
    *reinterpret_cast<bf16x8*>(&As[arow + 64][akg]) = loadA(ga1, grow1, k0 + akg);
    *reinterpret_cast<bf16x8*>(&Bs[bn_][akg]) =
        *reinterpret_cast<const bf16x8*>(wrow + k0 + akg);
    __syncthreads();

    bf16x8 af[4], bg[2];
#pragma unroll
    for (int m = 0; m < 4; ++m)
      af[m] = *reinterpret_cast<const bf16x8*>(&As[wm * 64 + m * 16 + (lane & 15)][(lane >> 4) * 8]);
#pragma unroll
    for (int n = 0; n < 2; ++n)
      bg[n] = *reinterpret_cast<const bf16x8*>(&Bs[wn * 32 + n * 16 + (lane & 15)][(lane >> 4) * 8]);
#pragma unroll
    for (int m = 0; m < 4; ++m)
#pragma unroll
      for (int n = 0; n < 2; ++n)
        acc[m][n] = __builtin_amdgcn_mfma_f32_16x16x32_bf16(af[m], bg[n], acc[m][n], 0, 0, 0);
    __syncthreads();
  }

  const int rbase = row0 + wm * 64;
  const int cbase = col0 + wn * 32;
#pragma unroll
  for (int m = 0; m < 4; ++m)
#pragma unroll
    for (int n = 0; n < 2; ++n)
#pragma unroll
      for (int g = 0; g < 4; ++g) {
        int r = rbase + m * 16 + (lane >> 4) * 4 + g;
        if (r < nrows) {
          int c = cbase + n * 16 + (lane & 15);
          float x = fmaxf(acc[m][n][g], 0.f);
          if (MODE == 0) outb[(size_t)r * DOUT + c] = f32_bf16(x);
          else outf[(size_t)r * DOUT + c] = x;
        }
      }
}

// ---- launcher ------------------------------------------------------------

extern "C" void kernel_launch(void* const* d_in, const int* in_sizes, int n_in,
                              void* d_out, int out_size, void* d_ws, size_t ws_size,
                              hipStream_t stream) {
  const float* nf   = (const float*)d_in[0];
  const float* ef1  = (const float*)d_in[1];
  const float* ef2  = (const float*)d_in[2];
  const float* W1   = (const float*)d_in[3];
  const float* W2   = (const float*)d_in[4];
  const int* from1  = (const int*)d_in[5];
  const int* seg1   = (const int*)d_in[6];
  const int* self1  = (const int*)d_in[7];
  const int* from2  = (const int*)d_in[8];
  const int* seg2   = (const int*)d_in[9];
  const int* self2  = (const int*)d_in[10];
  float* out = (float*)d_out;

  char* w = (char*)d_ws;
  size_t o = 0;
  auto take = [&](size_t nb) -> char* {
    char* p = w + o;
    o += (nb + 255) & ~(size_t)255;
    return p;
  };
  // zero-region (one memset): cnt1, cnt2, nn, mark
  int* cnt1 = (int*)take((size_t)M1 * 4);
  int* cnt2 = (int*)take((size_t)BSZ * 4);
  int* mark = (int*)take((size_t)M1 * 4);
  int* nn   = (int*)take(256);
  size_t zero_bytes = o;
  int* off1     = (int*)take((size_t)(M1 + 1) * 4);
  int* cur1     = (int*)take((size_t)M1 * 4);
  int* order1   = (int*)take((size_t)E1 * 4);
  int* remap    = (int*)take((size_t)M1 * 4);
  int* needed   = (int*)take((size_t)8192 * 4);
  int* selfrow1 = (int*)take((size_t)8192 * 4);
  int* off2     = (int*)take((size_t)(BSZ + 1) * 4);
  int* cur2     = (int*)take((size_t)BSZ * 4);
  int* order2   = (int*)take((size_t)E2 * 4);
  unsigned short* Wb1   = (unsigned short*)take((size_t)WELEMS * 2);
  unsigned short* Wb2   = (unsigned short*)take((size_t)WELEMS * 2);
  unsigned short* agg1c = (unsigned short*)take((size_t)8192 * DAGG * 2);
  unsigned short* agg2  = (unsigned short*)take((size_t)8192 * DAGG * 2);
  unsigned short* h1c   = (unsigned short*)take((size_t)8192 * DOUT * 2);

  hipMemsetAsync(d_ws, 0, zero_bytes, stream);

  convw_kernel<<<CDIV(2 * WELEMS / 4, 256), 256, 0, stream>>>(W1, W2, Wb1, Wb2);
  mark_kernel<<<CDIV(BSZ, 256), 256, 0, stream>>>(self2, mark);
  compact_kernel<<<CDIV(M1, 256), 256, 0, stream>>>(mark, self1, remap, needed, selfrow1, nn);
  count_both_kernel<<<CDIV(E1 + E2, 256), 256, 0, stream>>>(seg1, mark, cnt1, seg2, cnt2);
  scan_both_kernel<<<2, 1024, 0, stream>>>(cnt1, off1, cur1, cnt2, off2, cur2);
  scatter_both_kernel<<<CDIV(E1 + E2, 256), 256, 0, stream>>>(seg1, mark, cur1, order1,
                                                              seg2, cur2, order2);
  agg_both_kernel<<<16384, 384, 0, stream>>>(needed, nn, off1, order1, from1, ef1, agg1c,
                                             off2, order2, from2, ef2, agg2, nf);

  gemm_mfma_kernel<0><<<dim3(64, 4), 256, 0, stream>>>(nf, nullptr, selfrow1, nullptr,
                                                       agg1c, Wb1, nullptr, h1c, nn, 0);
  gemm_mfma_kernel<1><<<dim3(64, 4), 256, 0, stream>>>(nullptr, h1c, self2, remap,
                                                       agg2, Wb2, out, nullptr, nullptr, BSZ);
}

// Round 3
// 192.074 us; speedup vs baseline: 1.6398x; 1.2396x over previous
//
#include <hip/hip_runtime.h>
#include <hip/hip_bf16.h>

#define N_NODES 100000
#define DN      256
#define DE      128
#define DOUT    256
#define M1      32768
#define BSZ     8192
#define E1      327680
#define E2      81920
#define DIN     640
#define DAGG    384

#define CDIV(a,b) (((a)+(b)-1)/(b))

typedef __attribute__((ext_vector_type(8))) short bf16x8;
typedef __attribute__((ext_vector_type(4))) float f32x4;
typedef __attribute__((ext_vector_type(2))) float f32x2;
typedef __attribute__((ext_vector_type(4))) unsigned short u16x4;
typedef __attribute__((ext_vector_type(2))) unsigned short u16x2;

__device__ __forceinline__ unsigned short f32_bf16(float f) {
  unsigned u = __float_as_uint(f);
  unsigned r = (u + 0x7FFF + ((u >> 16) & 1)) >> 16;
  return (unsigned short)r;
}

// ---- bookkeeping kernels -------------------------------------------------

__global__ __launch_bounds__(256) void mark_kernel(const int* __restrict__ self2,
                                                   int* __restrict__ mark) {
  int i = blockIdx.x * 256 + threadIdx.x;
  if (i < BSZ) mark[self2[i]] = 1;
}

__global__ __launch_bounds__(256) void compact_kernel(const int* __restrict__ mark,
                                                      const int* __restrict__ self1,
                                                      int* __restrict__ remap,
                                                      int* __restrict__ needed,
                                                      int* __restrict__ selfrow1,
                                                      int* __restrict__ nn) {
  int m = blockIdx.x * 256 + threadIdx.x;
  if (m >= M1) return;
  if (mark[m]) {
    int p = atomicAdd(nn, 1);
    remap[m] = p;
    needed[p] = m;
    selfrow1[p] = self1[m];
  } else {
    remap[m] = -1;
  }
}

__global__ __launch_bounds__(256) void count_both_kernel(const int* __restrict__ seg1,
                                                         const int* __restrict__ mark,
                                                         int* __restrict__ cnt1,
                                                         const int* __restrict__ seg2,
                                                         int* __restrict__ cnt2) {
  int e = blockIdx.x * 256 + threadIdx.x;
  if (e < E1) {
    int s = seg1[e];
    if (mark[s]) atomicAdd(&cnt1[s], 1);
  } else if (e < E1 + E2) {
    int s = seg2[e - E1];
    atomicAdd(&cnt2[s], 1);
  }
}

// block 0: scan cnt1 (n=M1), block 1: scan cnt2 (n=BSZ). n divisible by 1024.
__global__ __launch_bounds__(1024) void scan_both_kernel(const int* __restrict__ cnt1,
                                                         int* __restrict__ off1,
                                                         int* __restrict__ cur1,
                                                         const int* __restrict__ cnt2,
                                                         int* __restrict__ off2,
                                                         int* __restrict__ cur2) {
  const int* cnt; int* off; int* cur; int n;
  if (blockIdx.x == 0) { cnt = cnt1; off = off1; cur = cur1; n = M1; }
  else                 { cnt = cnt2; off = off2; cur = cur2; n = BSZ; }
  int t = threadIdx.x;
  int per = n >> 10;
  int base = t * per;
  int s = 0;
  for (int j = 0; j < per; ++j) s += cnt[base + j];
  int lane = t & 63, wid = t >> 6;
  int v = s;
  for (int d = 1; d < 64; d <<= 1) {
    int u = __shfl_up(v, d);
    if (lane >= d) v += u;
  }
  __shared__ int wsum[16];
  if (lane == 63) wsum[wid] = v;
  __syncthreads();
  if (t == 0) {
    int run = 0;
    for (int wi = 0; wi < 16; ++wi) { int x = wsum[wi]; wsum[wi] = run; run += x; }
    off[n] = run;
  }
  __syncthreads();
  int excl = wsum[wid] + (v - s);
  int run = excl;
  for (int j = 0; j < per; ++j) {
    off[base + j] = run;
    cur[base + j] = run;
    run += cnt[base + j];
  }
}

__global__ __launch_bounds__(256) void scatter_both_kernel(const int* __restrict__ seg1,
                                                           const int* __restrict__ mark,
                                                           int* __restrict__ cur1,
                                                           int* __restrict__ order1,
                                                           const int* __restrict__ seg2,
                                                           int* __restrict__ cur2,
                                                           int* __restrict__ order2) {
  int e = blockIdx.x * 256 + threadIdx.x;
  if (e < E1) {
    int s = seg1[e];
    if (mark[s]) {
      int p = atomicAdd(&cur1[s], 1);
      order1[p] = e;
    }
  } else if (e < E1 + E2) {
    int e2 = e - E1;
    int s = seg2[e2];
    int p = atomicAdd(&cur2[s], 1);
    order2[p] = e2;
  }
}

// ---- aggregation: ONE WAVE per output segment, both layers ---------------
// Lane l owns nf cols [4l..4l+3] (f32x4) and ef cols [2l..2l+1] (f32x2).
// Edge ids/from-ids are loaded 64-at-a-time lane-parallel, broadcast via shfl;
// gathers are grouped x4 so 8 independent loads are in flight per wait.
// agg row layout (bf16): [0..255] node-feat sum, [256..383] edge-feat sum.

__global__ __launch_bounds__(256) void agg_both_kernel(const int* __restrict__ needed,
                                                       const int* __restrict__ nn_dev,
                                                       const int* __restrict__ off1,
                                                       const int* __restrict__ order1,
                                                       const int* __restrict__ from1,
                                                       const float* __restrict__ ef1,
                                                       unsigned short* __restrict__ agg1,
                                                       const int* __restrict__ off2,
                                                       const int* __restrict__ order2,
                                                       const int* __restrict__ from2,
                                                       const float* __restrict__ ef2,
                                                       unsigned short* __restrict__ agg2,
                                                       const float* __restrict__ nf) {
  int w = (blockIdx.x * 256 + threadIdx.x) >> 6;  // global wave id = segment slot
  int l = threadIdx.x & 63;
  const int* off; const int* order; const int* from_idx; const float* ef;
  unsigned short* aggout; int r, seg;
  if (w < 8192) {
    if (w >= *nn_dev) return;
    r = w; seg = needed[w];
    off = off1; order = order1; from_idx = from1; ef = ef1; aggout = agg1;
  } else {
    r = w - 8192; seg = r;
    off = off2; order = order2; from_idx = from2; ef = ef2; aggout = agg2;
  }
  int e0 = off[seg], e1c = off[seg + 1];

  f32x4 accn = (f32x4)0.f;
  f32x2 accf = (f32x2)0.f;

  for (int c0 = e0; c0 < e1c; c0 += 64) {
    int nc = min(64, e1c - c0);
    int eid = 0, fid = 0;
    if (l < nc) {
      eid = order[c0 + l];
      fid = from_idx[eid];
    }
    int j = 0;
    for (; j + 4 <= nc; j += 4) {
      int f0 = __shfl(fid, j),     f1 = __shfl(fid, j + 1);
      int f2 = __shfl(fid, j + 2), f3 = __shfl(fid, j + 3);
      int g0 = __shfl(eid, j),     g1 = __shfl(eid, j + 1);
      int g2 = __shfl(eid, j + 2), g3 = __shfl(eid, j + 3);
      f32x4 a0 = *reinterpret_cast<const f32x4*>(nf + (size_t)f0 * 256 + l * 4);
      f32x4 a1 = *reinterpret_cast<const f32x4*>(nf + (size_t)f1 * 256 + l * 4);
      f32x4 a2 = *reinterpret_cast<const f32x4*>(nf + (size_t)f2 * 256 + l * 4);
      f32x4 a3 = *reinterpret_cast<const f32x4*>(nf + (size_t)f3 * 256 + l * 4);
      f32x2 b0 = *reinterpret_cast<const f32x2*>(ef + (size_t)g0 * 128 + l * 2);
      f32x2 b1 = *reinterpret_cast<const f32x2*>(ef + (size_t)g1 * 128 + l * 2);
      f32x2 b2 = *reinterpret_cast<const f32x2*>(ef + (size_t)g2 * 128 + l * 2);
      f32x2 b3 = *reinterpret_cast<const f32x2*>(ef + (size_t)g3 * 128 + l * 2);
      accn += (a0 + a1) + (a2 + a3);
      accf += (b0 + b1) + (b2 + b3);
    }
    for (; j < nc; ++j) {
      int fj = __shfl(fid, j);
      int gj = __shfl(eid, j);
      accn += *reinterpret_cast<const f32x4*>(nf + (size_t)fj * 256 + l * 4);
      accf += *reinterpret_cast<const f32x2*>(ef + (size_t)gj * 128 + l * 2);
    }
  }

  unsigned short* orow = aggout + (size_t)r * DAGG;
  u16x4 on;
  on[0] = f32_bf16(accn[0]); on[1] = f32_bf16(accn[1]);
  on[2] = f32_bf16(accn[2]); on[3] = f32_bf16(accn[3]);
  *reinterpret_cast<u16x4*>(orow + l * 4) = on;
  u16x2 oe;
  oe[0] = f32_bf16(accf[0]); oe[1] = f32_bf16(accf[1]);
  *reinterpret_cast<u16x2*>(orow + 256 + l * 2) = oe;
}

// ---- W f32 -> bf16 conversion (both weight matrices, flat) ---------------

#define WELEMS (DOUT * DIN)

__global__ __launch_bounds__(256) void convw_kernel(const float* __restrict__ W1,
                                                    const float* __restrict__ W2,
                                                    unsigned short* __restrict__ Wb1,
                                                    unsigned short* __restrict__ Wb2) {
  int i = (blockIdx.x * 256 + threadIdx.x) * 4;
  const float* s; unsigned short* d; int o;
  if (i < WELEMS) { s = W1; d = Wb1; o = i; }
  else if (i < 2 * WELEMS) { s = W2; d = Wb2; o = i - WELEMS; }
  else return;
  f32x4 v = *reinterpret_cast<const f32x4*>(s + o);
  d[o + 0] = f32_bf16(v[0]);
  d[o + 1] = f32_bf16(v[1]);
  d[o + 2] = f32_bf16(v[2]);
  d[o + 3] = f32_bf16(v[3]);
}

// ---- MFMA GEMM: out[r,:] = relu([tabrow(r) | agg[r]] @ W^T) --------------
// MODE 0 (layer1): table = nf (f32), row = i1[r];        out = bf16 h1
// MODE 1 (layer2): table = h1 (bf16), row = i2[i1[r]];   out = f32 final
// Tile: BM=128, BN=64, BK=32; 4 waves in 2x2; per wave 4x2 frags of 16x16.

template<int MODE>
__global__ __launch_bounds__(256) void gemm_mfma_kernel(const float* __restrict__ tabf,
                                                        const unsigned short* __restrict__ tabb,
                                                        const int* __restrict__ i1,
                                                        const int* __restrict__ i2,
                                                        const unsigned short* __restrict__ agg,
                                                        const unsigned short* __restrict__ Wb,
                                                        float* __restrict__ outf,
                                                        unsigned short* __restrict__ outb,
                                                        const int* __restrict__ nn_dev,
                                                        int nrows_c) {
  const int nrows = nn_dev ? *nn_dev : nrows_c;
  const int row0 = blockIdx.x * 128;
  if (row0 >= nrows) return;
  const int col0 = blockIdx.y * 64;

  __shared__ unsigned short As[128][40];  // 80B row stride: 16B-aligned, low conflict
  __shared__ unsigned short Bs[64][40];

  const int t = threadIdx.x;
  const int lane = t & 63, wid = t >> 6;
  const int wm = wid >> 1, wn = wid & 1;

  // staging geometry: thread t stages A rows (t>>2) and (t>>2)+64, k-oct (t&3)*8
  const int arow = t >> 2;
  const int akg = (t & 3) * 8;
  const int grow0 = row0 + arow;
  const int grow1 = row0 + arow + 64;
  int ga0 = -1, ga1 = -1;
  if (grow0 < nrows) { int x = i1[grow0]; ga0 = (MODE == 1) ? i2[x] : x; }
  if (grow1 < nrows) { int x = i1[grow1]; ga1 = (MODE == 1) ? i2[x] : x; }

  const int bn_ = t >> 2;  // B stage: col (t>>2), same k-oct
  const unsigned short* wrow = Wb + (size_t)(col0 + bn_) * DIN;

  f32x4 acc[4][2];
#pragma unroll
  for (int m = 0; m < 4; ++m)
#pragma unroll
    for (int n = 0; n < 2; ++n) acc[m][n] = (f32x4)0.f;

  auto loadA = [&](int ga, int grow, int k) -> bf16x8 {
    bf16x8 v = (bf16x8)(short)0;
    if (ga < 0) return v;
    if (k < 256) {
      if (MODE == 0) {
        const float* s = tabf + (size_t)ga * 256 + k;
        f32x4 x0 = *reinterpret_cast<const f32x4*>(s);
        f32x4 x1 = *reinterpret_cast<const f32x4*>(s + 4);
#pragma unroll
        for (int j = 0; j < 4; ++j) {
          v[j] = (short)f32_bf16(x0[j]);
          v[4 + j] = (short)f32_bf16(x1[j]);
        }
      } else {
        v = *reinterpret_cast<const bf16x8*>(tabb + (size_t)ga * 256 + k);
      }
    } else {
      v = *reinterpret_cast<const bf16x8*>(agg + (size_t)grow * DAGG + (k - 256));
    }
    return v;
  };

  for (int k0 = 0; k0 < DIN; k0 += 32) {
    *reinterpret_cast<bf16x8*>(&As[arow][akg]) = loadA(ga0, grow0, k0 + akg);
    *reinterpret_cast<bf16x8*>(&As[arow + 64][akg]) = loadA(ga1, grow1, k0 + akg);
    *reinterpret_cast<bf16x8*>(&Bs[bn_][akg]) =
        *reinterpret_cast<const bf16x8*>(wrow + k0 + akg);
    __syncthreads();

    bf16x8 af[4], bg[2];
#pragma unroll
    for (int m = 0; m < 4; ++m)
      af[m] = *reinterpret_cast<const bf16x8*>(&As[wm * 64 + m * 16 + (lane & 15)][(lane >> 4) * 8]);
#pragma unroll
    for (int n = 0; n < 2; ++n)
      bg[n] = *reinterpret_cast<const bf16x8*>(&Bs[wn * 32 + n * 16 + (lane & 15)][(lane >> 4) * 8]);
#pragma unroll
    for (int m = 0; m < 4; ++m)
#pragma unroll
      for (int n = 0; n < 2; ++n)
        acc[m][n] = __builtin_amdgcn_mfma_f32_16x16x32_bf16(af[m], bg[n], acc[m][n], 0, 0, 0);
    __syncthreads();
  }

  const int rbase = row0 + wm * 64;
  const int cbase = col0 + wn * 32;
#pragma unroll
  for (int m = 0; m < 4; ++m)
#pragma unroll
    for (int n = 0; n < 2; ++n)
#pragma unroll
      for (int g = 0; g < 4; ++g) {
        int r = rbase + m * 16 + (lane >> 4) * 4 + g;
        if (r < nrows) {
          int c = cbase + n * 16 + (lane & 15);
          float x = fmaxf(acc[m][n][g], 0.f);
          if (MODE == 0) outb[(size_t)r * DOUT + c] = f32_bf16(x);
          else outf[(size_t)r * DOUT + c] = x;
        }
      }
}

// ---- launcher ------------------------------------------------------------

extern "C" void kernel_launch(void* const* d_in, const int* in_sizes, int n_in,
                              void* d_out, int out_size, void* d_ws, size_t ws_size,
                              hipStream_t stream) {
  const float* nf   = (const float*)d_in[0];
  const float* ef1  = (const float*)d_in[1];
  const float* ef2  = (const float*)d_in[2];
  const float* W1   = (const float*)d_in[3];
  const float* W2   = (const float*)d_in[4];
  const int* from1  = (const int*)d_in[5];
  const int* seg1   = (const int*)d_in[6];
  const int* self1  = (const int*)d_in[7];
  const int* from2  = (const int*)d_in[8];
  const int* seg2   = (const int*)d_in[9];
  const int* self2  = (const int*)d_in[10];
  float* out = (float*)d_out;

  char* w = (char*)d_ws;
  size_t o = 0;
  auto take = [&](size_t nb) -> char* {
    char* p = w + o;
    o += (nb + 255) & ~(size_t)255;
    return p;
  };
  // zero-region (one memset): cnt1, cnt2, mark, nn
  int* cnt1 = (int*)take((size_t)M1 * 4);
  int* cnt2 = (int*)take((size_t)BSZ * 4);
  int* mark = (int*)take((size_t)M1 * 4);
  int* nn   = (int*)take(256);
  size_t zero_bytes = o;
  int* off1     = (int*)take((size_t)(M1 + 1) * 4);
  int* cur1     = (int*)take((size_t)M1 * 4);
  int* order1   = (int*)take((size_t)E1 * 4);
  int* remap    = (int*)take((size_t)M1 * 4);
  int* needed   = (int*)take((size_t)8192 * 4);
  int* selfrow1 = (int*)take((size_t)8192 * 4);
  int* off2     = (int*)take((size_t)(BSZ + 1) * 4);
  int* cur2     = (int*)take((size_t)BSZ * 4);
  int* order2   = (int*)take((size_t)E2 * 4);
  unsigned short* Wb1   = (unsigned short*)take((size_t)WELEMS * 2);
  unsigned short* Wb2   = (unsigned short*)take((size_t)WELEMS * 2);
  unsigned short* agg1c = (unsigned short*)take((size_t)8192 * DAGG * 2);
  unsigned short* agg2  = (unsigned short*)take((size_t)8192 * DAGG * 2);
  unsigned short* h1c   = (unsigned short*)take((size_t)8192 * DOUT * 2);

  hipMemsetAsync(d_ws, 0, zero_bytes, stream);

  convw_kernel<<<CDIV(2 * WELEMS / 4, 256), 256, 0, stream>>>(W1, W2, Wb1, Wb2);
  mark_kernel<<<CDIV(BSZ, 256), 256, 0, stream>>>(self2, mark);
  compact_kernel<<<CDIV(M1, 256), 256, 0, stream>>>(mark, self1, remap, needed, selfrow1, nn);
  count_both_kernel<<<CDIV(E1 + E2, 256), 256, 0, stream>>>(seg1, mark, cnt1, seg2, cnt2);
  scan_both_kernel<<<2, 1024, 0, stream>>>(cnt1, off1, cur1, cnt2, off2, cur2);
  scatter_both_kernel<<<CDIV(E1 + E2, 256), 256, 0, stream>>>(seg1, mark, cur1, order1,
                                                              seg2, cur2, order2);
  agg_both_kernel<<<4096, 256, 0, stream>>>(needed, nn, off1, order1, from1, ef1, agg1c,
                                            off2, order2, from2, ef2, agg2, nf);

  gemm_mfma_kernel<0><<<dim3(64, 4), 256, 0, stream>>>(nf, nullptr, selfrow1, nullptr,
                                                       agg1c, Wb1, nullptr, h1c, nn, 0);
  gemm_mfma_kernel<1><<<dim3(64, 4), 256, 0, stream>>>(nullptr, h1c, self2, remap,
                                                       agg2, Wb2, out, nullptr, nullptr, BSZ);
}

// Round 4
// 130.278 us; speedup vs baseline: 2.4177x; 1.4743x over previous
//
#include <hip/hip_runtime.h>
#include <hip/hip_bf16.h>

#define N_NODES 100000
#define DN      256
#define DE      128
#define DOUT    256
#define M1      32768
#define BSZ     8192
#define E1      327680
#define E2      81920
#define DIN     640
#define DAGG    384
#define WELEMS  (DOUT * DIN)

#define CDIV(a,b) (((a)+(b)-1)/(b))

// zero region: cnt1[M1] cnt2[BSZ] mark[M1] nn[64] — contiguous ints at ws base
#define ZERO_INTS (M1 + BSZ + M1 + 64)
#define S1_ZB 73            // CDIV(ZERO_INTS, 1024)
#define S1_CB 80            // 2*WELEMS / 4 / 1024
#define S2_MB 8             // BSZ / 1024
#define S2_CB 400           // (E1+E2) / 1024
#define S3_KB 32            // M1 / 1024

typedef __attribute__((ext_vector_type(8))) short bf16x8;
typedef __attribute__((ext_vector_type(4))) float f32x4;
typedef __attribute__((ext_vector_type(2))) float f32x2;
typedef __attribute__((ext_vector_type(4))) unsigned short u16x4;
typedef __attribute__((ext_vector_type(2))) unsigned short u16x2;

__device__ __forceinline__ unsigned short f32_bf16(float f) {
  unsigned u = __float_as_uint(f);
  unsigned r = (u + 0x7FFF + ((u >> 16) & 1)) >> 16;
  return (unsigned short)r;
}

// ---- setup1: zero bookkeeping region + convert W1/W2 to bf16 --------------

__global__ __launch_bounds__(1024) void setup1_kernel(int* __restrict__ zbase,
                                                      const float* __restrict__ W1,
                                                      const float* __restrict__ W2,
                                                      unsigned short* __restrict__ Wb1,
                                                      unsigned short* __restrict__ Wb2) {
  int b = blockIdx.x, t = threadIdx.x;
  if (b < S1_ZB) {
    int i = b * 1024 + t;
    if (i < ZERO_INTS) zbase[i] = 0;
  } else {
    int i = ((b - S1_ZB) * 1024 + t) * 4;
    const float* s; unsigned short* d; int o;
    if (i < WELEMS) { s = W1; d = Wb1; o = i; }
    else { s = W2; d = Wb2; o = i - WELEMS; }
    f32x4 v = *reinterpret_cast<const f32x4*>(s + o);
    u16x4 r;
    r[0] = f32_bf16(v[0]); r[1] = f32_bf16(v[1]);
    r[2] = f32_bf16(v[2]); r[3] = f32_bf16(v[3]);
    *reinterpret_cast<u16x4*>(d + o) = r;
  }
}

// ---- setup2: mark live layer-1 segments + count ALL edges per segment -----

__global__ __launch_bounds__(1024) void setup2_kernel(const int* __restrict__ self2,
                                                      int* __restrict__ mark,
                                                      const int* __restrict__ seg1,
                                                      int* __restrict__ cnt1,
                                                      const int* __restrict__ seg2,
                                                      int* __restrict__ cnt2) {
  int b = blockIdx.x, t = threadIdx.x;
  if (b < S2_MB) {
    mark[self2[b * 1024 + t]] = 1;
  } else {
    int e = (b - S2_MB) * 1024 + t;
    if (e < E1) atomicAdd(&cnt1[seg1[e]], 1);
    else atomicAdd(&cnt2[seg2[e - E1]], 1);
  }
}

// ---- setup3: compact marked segments + exclusive scans --------------------

__device__ __forceinline__ void scan1024(const int* __restrict__ cnt,
                                         int* __restrict__ off,
                                         int* __restrict__ cur,
                                         int n, int* wsum) {
  int t = threadIdx.x;
  int per = n >> 10;
  int base = t * per;
  int s = 0;
  for (int j = 0; j < per; ++j) s += cnt[base + j];
  int lane = t & 63, wid = t >> 6;
  int v = s;
  for (int d = 1; d < 64; d <<= 1) {
    int u = __shfl_up(v, d);
    if (lane >= d) v += u;
  }
  if (lane == 63) wsum[wid] = v;
  __syncthreads();
  if (t == 0) {
    int run = 0;
    for (int wi = 0; wi < 16; ++wi) { int x = wsum[wi]; wsum[wi] = run; run += x; }
    off[n] = run;
  }
  __syncthreads();
  int excl = wsum[wid] + (v - s);
  int run = excl;
  for (int j = 0; j < per; ++j) {
    off[base + j] = run;
    cur[base + j] = run;
    run += cnt[base + j];
  }
}

__global__ __launch_bounds__(1024) void setup3_kernel(const int* __restrict__ mark,
                                                      const int* __restrict__ self1,
                                                      int* __restrict__ remap,
                                                      int* __restrict__ needed,
                                                      int* __restrict__ selfrow1,
                                                      int* __restrict__ nn,
                                                      const int* __restrict__ cnt1,
                                                      int* __restrict__ off1,
                                                      int* __restrict__ cur1,
                                                      const int* __restrict__ cnt2,
                                                      int* __restrict__ off2,
                                                      int* __restrict__ cur2) {
  __shared__ int wsum[16];
  int b = blockIdx.x;
  if (b < S3_KB) {
    int m = b * 1024 + threadIdx.x;
    if (mark[m]) {
      int p = atomicAdd(nn, 1);
      remap[m] = p;
      needed[p] = m;
      selfrow1[p] = self1[m];
    }
  } else if (b == S3_KB) {
    scan1024(cnt1, off1, cur1, M1, wsum);
  } else {
    scan1024(cnt2, off2, cur2, BSZ, wsum);
  }
}

// ---- setup4: scatter edge ids into CSR order ------------------------------

__global__ __launch_bounds__(1024) void setup4_kernel(const int* __restrict__ seg1,
                                                      int* __restrict__ cur1,
                                                      int* __restrict__ order1,
                                                      const int* __restrict__ seg2,
                                                      int* __restrict__ cur2,
                                                      int* __restrict__ order2) {
  int e = blockIdx.x * 1024 + threadIdx.x;
  if (e < E1) {
    int p = atomicAdd(&cur1[seg1[e]], 1);
    order1[p] = e;
  } else {
    int e2 = e - E1;
    int p = atomicAdd(&cur2[seg2[e2]], 1);
    order2[p] = e2;
  }
}

// ---- aggregation: ONE WAVE per output segment, both layers ---------------
// Lane l owns nf cols [4l..4l+3] (f32x4) and ef cols [2l..2l+1] (f32x2).

__global__ __launch_bounds__(256) void agg_both_kernel(const int* __restrict__ needed,
                                                       const int* __restrict__ nn_dev,
                                                       const int* __restrict__ off1,
                                                       const int* __restrict__ order1,
                                                       const int* __restrict__ from1,
                                                       const float* __restrict__ ef1,
                                                       unsigned short* __restrict__ agg1,
                                                       const int* __restrict__ off2,
                                                       const int* __restrict__ order2,
                                                       const int* __restrict__ from2,
                                                       const float* __restrict__ ef2,
                                                       unsigned short* __restrict__ agg2,
                                                       const float* __restrict__ nf) {
  int w = (blockIdx.x * 256 + threadIdx.x) >> 6;
  int l = threadIdx.x & 63;
  const int* off; const int* order; const int* from_idx; const float* ef;
  unsigned short* aggout; int r, seg;
  if (w < 8192) {
    if (w >= *nn_dev) return;
    r = w; seg = needed[w];
    off = off1; order = order1; from_idx = from1; ef = ef1; aggout = agg1;
  } else {
    r = w - 8192; seg = r;
    off = off2; order = order2; from_idx = from2; ef = ef2; aggout = agg2;
  }
  int e0 = off[seg], e1c = off[seg + 1];

  f32x4 accn = (f32x4)0.f;
  f32x2 accf = (f32x2)0.f;

  for (int c0 = e0; c0 < e1c; c0 += 64) {
    int nc = min(64, e1c - c0);
    int eid = 0, fid = 0;
    if (l < nc) {
      eid = order[c0 + l];
      fid = from_idx[eid];
    }
    int j = 0;
    for (; j + 4 <= nc; j += 4) {
      int f0 = __shfl(fid, j),     f1 = __shfl(fid, j + 1);
      int f2 = __shfl(fid, j + 2), f3 = __shfl(fid, j + 3);
      int g0 = __shfl(eid, j),     g1 = __shfl(eid, j + 1);
      int g2 = __shfl(eid, j + 2), g3 = __shfl(eid, j + 3);
      f32x4 a0 = *reinterpret_cast<const f32x4*>(nf + (size_t)f0 * 256 + l * 4);
      f32x4 a1 = *reinterpret_cast<const f32x4*>(nf + (size_t)f1 * 256 + l * 4);
      f32x4 a2 = *reinterpret_cast<const f32x4*>(nf + (size_t)f2 * 256 + l * 4);
      f32x4 a3 = *reinterpret_cast<const f32x4*>(nf + (size_t)f3 * 256 + l * 4);
      f32x2 b0 = *reinterpret_cast<const f32x2*>(ef + (size_t)g0 * 128 + l * 2);
      f32x2 b1 = *reinterpret_cast<const f32x2*>(ef + (size_t)g1 * 128 + l * 2);
      f32x2 b2 = *reinterpret_cast<const f32x2*>(ef + (size_t)g2 * 128 + l * 2);
      f32x2 b3 = *reinterpret_cast<const f32x2*>(ef + (size_t)g3 * 128 + l * 2);
      accn += (a0 + a1) + (a2 + a3);
      accf += (b0 + b1) + (b2 + b3);
    }
    for (; j < nc; ++j) {
      int fj = __shfl(fid, j);
      int gj = __shfl(eid, j);
      accn += *reinterpret_cast<const f32x4*>(nf + (size_t)fj * 256 + l * 4);
      accf += *reinterpret_cast<const f32x2*>(ef + (size_t)gj * 128 + l * 2);
    }
  }

  unsigned short* orow = aggout + (size_t)r * DAGG;
  u16x4 on;
  on[0] = f32_bf16(accn[0]); on[1] = f32_bf16(accn[1]);
  on[2] = f32_bf16(accn[2]); on[3] = f32_bf16(accn[3]);
  *reinterpret_cast<u16x4*>(orow + l * 4) = on;
  u16x2 oe;
  oe[0] = f32_bf16(accf[0]); oe[1] = f32_bf16(accf[1]);
  *reinterpret_cast<u16x2*>(orow + 256 + l * 2) = oe;
}

// ---- MFMA GEMM: out[r,:] = relu([tabrow(r) | agg[r]] @ W^T) --------------
// MODE 0 (layer1): table = nf (f32), row = i1[r];        out = bf16 h1
// MODE 1 (layer2): table = h1 (bf16), row = i2[i1[r]];   out = f32 final
// Tile BM=64, BN=64, BK=64; 4 waves 2x2, each 32x32 (2x2 frags of 16x16x32).
// Register prefetch of next K-tile issued before the MFMA phase.

template<int MODE>
__global__ __launch_bounds__(256, 2) void gemm_mfma_kernel(const float* __restrict__ tabf,
                                                           const unsigned short* __restrict__ tabb,
                                                           const int* __restrict__ i1,
                                                           const int* __restrict__ i2,
                                                           const unsigned short* __restrict__ agg,
                                                           const unsigned short* __restrict__ Wb,
                                                           float* __restrict__ outf,
                                                           unsigned short* __restrict__ outb,
                                                           const int* __restrict__ nn_dev,
                                                           int nrows_c) {
  const int nrows = nn_dev ? *nn_dev : nrows_c;
  const int row0 = blockIdx.x * 64;
  if (row0 >= nrows) return;
  const int col0 = blockIdx.y * 64;

  __shared__ unsigned short As[64][72];  // 144B row stride: 16B aligned, 2-way max
  __shared__ unsigned short Bs[64][72];

  const int t = threadIdx.x;
  const int lane = t & 63, wid = t >> 6;
  const int wm = wid >> 1, wn = wid & 1;

  // staging: thread t -> tile row (t>>2), k-cols (t&3)*16 .. +15
  const int srow = t >> 2;
  const int scol = (t & 3) * 16;
  const int grow = row0 + srow;
  int ga = -1;
  if (grow < nrows) { int x = i1[grow]; ga = (MODE == 1) ? i2[x] : x; }
  const unsigned short* wrow = Wb + (size_t)(col0 + srow) * DIN + scol;
  const float* tabrow_f = (MODE == 0 && ga >= 0) ? tabf + (size_t)ga * 256 : nullptr;
  const unsigned short* tabrow_b = (MODE == 1 && ga >= 0) ? tabb + (size_t)ga * 256 : nullptr;
  const unsigned short* aggrow = agg + (size_t)grow * DAGG;

  f32x4 acc[2][2];
#pragma unroll
  for (int m = 0; m < 2; ++m)
#pragma unroll
    for (int n = 0; n < 2; ++n) acc[m][n] = (f32x4)0.f;

  bf16x8 ra0, ra1, rb0, rb1;

  auto loadA = [&](int k0, bf16x8& r0, bf16x8& r1) {
    int k = k0 + scol;
    if (ga < 0) { r0 = (bf16x8)(short)0; r1 = (bf16x8)(short)0; return; }
    if (k < 256) {
      if (MODE == 0) {
        const float* s = tabrow_f + k;
        f32x4 x0 = *reinterpret_cast<const f32x4*>(s);
        f32x4 x1 = *reinterpret_cast<const f32x4*>(s + 4);
        f32x4 x2 = *reinterpret_cast<const f32x4*>(s + 8);
        f32x4 x3 = *reinterpret_cast<const f32x4*>(s + 12);
#pragma unroll
        for (int j = 0; j < 4; ++j) {
          r0[j] = (short)f32_bf16(x0[j]); r0[4 + j] = (short)f32_bf16(x1[j]);
          r1[j] = (short)f32_bf16(x2[j]); r1[4 + j] = (short)f32_bf16(x3[j]);
        }
      } else {
        r0 = *reinterpret_cast<const bf16x8*>(tabrow_b + k);
        r1 = *reinterpret_cast<const bf16x8*>(tabrow_b + k + 8);
      }
    } else {
      r0 = *reinterpret_cast<const bf16x8*>(aggrow + (k - 256));
      r1 = *reinterpret_cast<const bf16x8*>(aggrow + (k - 256) + 8);
    }
  };

  loadA(0, ra0, ra1);
  rb0 = *reinterpret_cast<const bf16x8*>(wrow);
  rb1 = *reinterpret_cast<const bf16x8*>(wrow + 8);

  for (int k0 = 0; k0 < DIN; k0 += 64) {
    *reinterpret_cast<bf16x8*>(&As[srow][scol]) = ra0;
    *reinterpret_cast<bf16x8*>(&As[srow][scol + 8]) = ra1;
    *reinterpret_cast<bf16x8*>(&Bs[srow][scol]) = rb0;
    *reinterpret_cast<bf16x8*>(&Bs[srow][scol + 8]) = rb1;
    __syncthreads();

    if (k0 + 64 < DIN) {  // issue next tile's loads before MFMA phase
      loadA(k0 + 64, ra0, ra1);
      rb0 = *reinterpret_cast<const bf16x8*>(wrow + k0 + 64);
      rb1 = *reinterpret_cast<const bf16x8*>(wrow + k0 + 64 + 8);
    }

#pragma unroll
    for (int ks = 0; ks < 2; ++ks) {
      bf16x8 af[2], bg[2];
#pragma unroll
      for (int m = 0; m < 2; ++m)
        af[m] = *reinterpret_cast<const bf16x8*>(
            &As[wm * 32 + m * 16 + (lane & 15)][ks * 32 + (lane >> 4) * 8]);
#pragma unroll
      for (int n = 0; n < 2; ++n)
        bg[n] = *reinterpret_cast<const bf16x8*>(
            &Bs[wn * 32 + n * 16 + (lane & 15)][ks * 32 + (lane >> 4) * 8]);
#pragma unroll
      for (int m = 0; m < 2; ++m)
#pragma unroll
        for (int n = 0; n < 2; ++n)
          acc[m][n] = __builtin_amdgcn_mfma_f32_16x16x32_bf16(af[m], bg[n], acc[m][n], 0, 0, 0);
    }
    __syncthreads();
  }

  const int rbase = row0 + wm * 32;
  const int cbase = col0 + wn * 32;
#pragma unroll
  for (int m = 0; m < 2; ++m)
#pragma unroll
    for (int n = 0; n < 2; ++n)
#pragma unroll
      for (int g = 0; g < 4; ++g) {
        int r = rbase + m * 16 + (lane >> 4) * 4 + g;
        if (r < nrows) {
          int c = cbase + n * 16 + (lane & 15);
          float x = fmaxf(acc[m][n][g], 0.f);
          if (MODE == 0) outb[(size_t)r * DOUT + c] = f32_bf16(x);
          else outf[(size_t)r * DOUT + c] = x;
        }
      }
}

// ---- launcher ------------------------------------------------------------

extern "C" void kernel_launch(void* const* d_in, const int* in_sizes, int n_in,
                              void* d_out, int out_size, void* d_ws, size_t ws_size,
                              hipStream_t stream) {
  const float* nf   = (const float*)d_in[0];
  const float* ef1  = (const float*)d_in[1];
  const float* ef2  = (const float*)d_in[2];
  const float* W1   = (const float*)d_in[3];
  const float* W2   = (const float*)d_in[4];
  const int* from1  = (const int*)d_in[5];
  const int* seg1   = (const int*)d_in[6];
  const int* self1  = (const int*)d_in[7];
  const int* from2  = (const int*)d_in[8];
  const int* seg2   = (const int*)d_in[9];
  const int* self2  = (const int*)d_in[10];
  float* out = (float*)d_out;

  char* w = (char*)d_ws;
  size_t o = 0;
  auto take = [&](size_t nb) -> char* {
    char* p = w + o;
    o += (nb + 255) & ~(size_t)255;
    return p;
  };
  // zero region (cleared by setup1): cnt1, cnt2, mark, nn — exactly ZERO_INTS ints
  int* cnt1 = (int*)take((size_t)M1 * 4);
  int* cnt2 = (int*)take((size_t)BSZ * 4);
  int* mark = (int*)take((size_t)M1 * 4);
  int* nn   = (int*)take(256);
  int* off1     = (int*)take((size_t)(M1 + 1) * 4);
  int* cur1     = (int*)take((size_t)M1 * 4);
  int* order1   = (int*)take((size_t)E1 * 4);
  int* remap    = (int*)take((size_t)M1 * 4);
  int* needed   = (int*)take((size_t)8192 * 4);
  int* selfrow1 = (int*)take((size_t)8192 * 4);
  int* off2     = (int*)take((size_t)(BSZ + 1) * 4);
  int* cur2     = (int*)take((size_t)BSZ * 4);
  int* order2   = (int*)take((size_t)E2 * 4);
  unsigned short* Wb1   = (unsigned short*)take((size_t)WELEMS * 2);
  unsigned short* Wb2   = (unsigned short*)take((size_t)WELEMS * 2);
  unsigned short* agg1c = (unsigned short*)take((size_t)8192 * DAGG * 2);
  unsigned short* agg2  = (unsigned short*)take((size_t)8192 * DAGG * 2);
  unsigned short* h1c   = (unsigned short*)take((size_t)8192 * DOUT * 2);

  setup1_kernel<<<S1_ZB + S1_CB, 1024, 0, stream>>>((int*)d_ws, W1, W2, Wb1, Wb2);
  setup2_kernel<<<S2_MB + S2_CB, 1024, 0, stream>>>(self2, mark, seg1, cnt1, seg2, cnt2);
  setup3_kernel<<<S3_KB + 2, 1024, 0, stream>>>(mark, self1, remap, needed, selfrow1, nn,
                                                cnt1, off1, cur1, cnt2, off2, cur2);
  setup4_kernel<<<S2_CB, 1024, 0, stream>>>(seg1, cur1, order1, seg2, cur2, order2);
  agg_both_kernel<<<4096, 256, 0, stream>>>(needed, nn, off1, order1, from1, ef1, agg1c,
                                            off2, order2, from2, ef2, agg2, nf);
  gemm_mfma_kernel<0><<<dim3(128, 4), 256, 0, stream>>>(nf, nullptr, selfrow1, nullptr,
                                                        agg1c, Wb1, nullptr, h1c, nn, 0);
  gemm_mfma_kernel<1><<<dim3(128, 4), 256, 0, stream>>>(nullptr, h1c, self2, remap,
                                                        agg2, Wb2, out, nullptr, nullptr, BSZ);
}